// Round 10
// baseline (52.474 us; speedup 1.0000x reference)
//
#include <hip/hip_runtime.h>

#define IN_SZ 108
#define NPIX (IN_SZ * IN_SZ)

typedef float f32x2 __attribute__((ext_vector_type(2)));

__device__ __forceinline__ float maskv(float x, float off, float end) {
    // sigmoid(10*(x-off)) - sigmoid(10*(x-end))
    float a = 1.0f / (1.0f + __expf(-10.0f * (x - off)));
    float b = 1.0f / (1.0f + __expf(-10.0f * (x - end)));
    return a - b;
}

__global__ __launch_bounds__(128) void attn_crop_kernel(
    const float* __restrict__ images,
    const float* __restrict__ locs,
    float* __restrict__ out)
{
    __shared__ float4 s_row[IN_SZ];   // wr0, wr1, r0*108 (bits), r1*108 (bits)

    const int blk = blockIdx.x;       // img*3 + ch
    const int img = blk / 3;
    const int tid = threadIdx.x;
    const int w   = tid >> 6;         // wave id (0..1)
    const int l   = tid & 63;         // lane

    // ---- per-image box ----
    const float l0 = locs[3 * img + 0];
    const float l1 = locs[3 * img + 1];
    const float l2 = locs[3 * img + 2];
    const float tx = 54.0f + truncf(l0 * 27.0f + 0.5f);
    const float ty = 54.0f + truncf(l1 * 27.0f + 0.5f);
    const float tl = 21.0f + truncf(l2 * 7.0f + 0.5f);
    const float w_off = fmaxf(tx - tl, 0.0f);
    const float h_off = fmaxf(ty - tl, 0.0f);
    const float w_end = fminf(tx + tl, 108.0f);
    const float h_end = fminf(ty + tl, 108.0f);

    // ---- row table: built once (one expf pass, threads 0..107) ----
    if (tid < IN_SZ) {
        float fj  = (float)tid;
        float sr  = w_off + (fj * (w_end - w_off - 1.0f)) / 107.0f;  // reference order
        float flr = fminf(fmaxf(floorf(sr), 0.0f), 107.0f);
        int   r0  = (int)flr;
        int   r1  = min(r0 + 1, 107);
        float fr  = sr - flr;
        float4 p;
        p.x = (1.0f - fr) * maskv((float)r0, w_off, w_end);
        p.y = fr * maskv((float)r1, w_off, w_end);
        p.z = __int_as_float(r0 * IN_SZ);
        p.w = __int_as_float(r1 * IN_SZ);
        s_row[tid] = p;
    }

    // ---- per-lane column params (cols 2l, 2l+1), loop-invariant ----
    const float cspan = h_end - h_off - 1.0f;
    const int kA = min(2 * l, 107), kB = min(2 * l + 1, 107);
    float scA  = h_off + ((float)kA * cspan) / 107.0f;
    float flA  = fminf(fmaxf(floorf(scA), 0.0f), 107.0f);
    int   c0A  = (int)flA;
    float fcA  = scA - flA;
    float wc0A = (1.0f - fcA) * maskv((float)c0A, h_off, h_end);
    float wc1A = fcA * maskv((float)min(c0A + 1, 107), h_off, h_end);
    float scB  = h_off + ((float)kB * cspan) / 107.0f;
    float flB  = fminf(fmaxf(floorf(scB), 0.0f), 107.0f);
    int   c0B  = (int)flB;
    float fcB  = scB - flB;
    float wc0B = (1.0f - fcB) * maskv((float)c0B, h_off, h_end);
    float wc1B = fcB * maskv((float)min(c0B + 1, 107), h_off, h_end);

    // q0..q3 after shfl = interpolated cols {2*li0, 2*li0+1, 2*li0+2, 2*li0+3}
    // col c0A = index 'par' in that window; c0B starts at par+d (d = c0B-c0A in {0,1})
    const int li0 = c0A >> 1;
    const int par = c0A & 1;
    const int sy  = par + (c0B - c0A);
    const float Wx0 = par ? 0.0f  : wc0A;
    const float Wx1 = par ? wc0A  : wc1A;
    const float Wx2 = par ? wc1A  : 0.0f;
    const float Wy0 = (sy == 0) ? wc0B : 0.0f;
    const float Wy1 = (sy == 0) ? wc1B : ((sy == 1) ? wc0B : 0.0f);
    const float Wy2 = (sy == 1) ? wc1B : ((sy == 2) ? wc0B : 0.0f);
    const float Wy3 = (sy == 2) ? wc1B : 0.0f;

    __syncthreads();

    const int colLoad = min(2 * l, 106);     // keep all lanes in-bounds
    const float* __restrict__ src = images + (size_t)blk * NPIX;
    float*       __restrict__ dstl = out    + (size_t)blk * NPIX + 2 * l;
    const int jb = 54 * w;                   // contiguous rows [jb, jb+54) per wave

    // ---- prologue: params + loads for rows jb, jb+1 ----
    float4 p0 = s_row[jb];
    float4 p1 = s_row[jb + 1];
    f32x2 A0 = *(const f32x2*)(src + __float_as_int(p0.z) + colLoad);
    f32x2 B0 = *(const f32x2*)(src + __float_as_int(p0.w) + colLoad);
    f32x2 A1 = *(const f32x2*)(src + __float_as_int(p1.z) + colLoad);
    f32x2 B1 = *(const f32x2*)(src + __float_as_int(p1.w) + colLoad);

    for (int jj = 0; jj < 54; ++jj) {
        // prefetch row jj+2 (distance-2 pipeline, as in the proven R6 structure)
        float4 p2 = p1;
        f32x2 A2 = A1, B2 = B1;
        if (jj < 52) {
            p2 = s_row[jb + jj + 2];
            A2 = *(const f32x2*)(src + __float_as_int(p2.z) + colLoad);
            B2 = *(const f32x2*)(src + __float_as_int(p2.w) + colLoad);
        }
        // fold rows first (wr0, wr1 wave-uniform), then cross-lane gather
        const float wr0 = p0.x, wr1 = p0.y;
        f32x2 M;
        M.x = A0.x * wr0 + B0.x * wr1;
        M.y = A0.y * wr0 + B0.y * wr1;
        float q0 = __shfl(M.x, li0);
        float q1 = __shfl(M.y, li0);
        float q2 = __shfl(M.x, li0 + 1);
        float q3 = __shfl(M.y, li0 + 1);
        f32x2 o;
        o.x = q0 * Wx0 + q1 * Wx1 + q2 * Wx2;
        o.y = q0 * Wy0 + q1 * Wy1 + q2 * Wy2 + q3 * Wy3;
        if (l < 54) *(f32x2*)(dstl + (jb + jj) * IN_SZ) = o;
        p0 = p1; A0 = A1; B0 = B1;
        p1 = p2; A1 = A2; B1 = B2;
    }
}

extern "C" void kernel_launch(void* const* d_in, const int* in_sizes, int n_in,
                              void* d_out, int out_size, void* d_ws, size_t ws_size,
                              hipStream_t stream) {
    const float* images = (const float*)d_in[0];
    const float* locs   = (const float*)d_in[1];
    float* out = (float*)d_out;
    const int nimg = in_sizes[1] / 3;   // locs is [nimg, 3]
    attn_crop_kernel<<<dim3(nimg * 3), dim3(128), 0, stream>>>(images, locs, out);
}

// Round 11
// 37.211 us; speedup vs baseline: 1.4102x; 1.4102x over previous
//
#include <hip/hip_runtime.h>

#define IN_SZ 108
#define NPIX (IN_SZ * IN_SZ)

typedef float f32x2 __attribute__((ext_vector_type(2)));
typedef float f32x4 __attribute__((ext_vector_type(4)));
typedef f32x4 f32x4u __attribute__((aligned(8)));   // 8B-aligned 16B load

__device__ __forceinline__ f32x4 ld4u(const float* p) { return *(const f32x4u*)p; }

__device__ __forceinline__ float maskv(float x, float off, float end) {
    // sigmoid(10*(x-off)) - sigmoid(10*(x-end))
    float a = 1.0f / (1.0f + __expf(-10.0f * (x - off)));
    float b = 1.0f / (1.0f + __expf(-10.0f * (x - end)));
    return a - b;
}

__global__ __launch_bounds__(256) void attn_crop_kernel(
    const float* __restrict__ images,
    const float* __restrict__ locs,
    float* __restrict__ out)
{
    __shared__ float4 s_row[IN_SZ];   // wr0, wr1, r0*108 (bits), r1*108 (bits)

    const int blk = blockIdx.x;       // img*3 + ch
    const int img = blk / 3;
    const int tid = threadIdx.x;
    const int w   = tid >> 6;         // wave id (0..3)
    const int l   = tid & 63;         // lane

    // ---- per-image box ----
    const float l0 = locs[3 * img + 0];
    const float l1 = locs[3 * img + 1];
    const float l2 = locs[3 * img + 2];
    const float tx = 54.0f + truncf(l0 * 27.0f + 0.5f);
    const float ty = 54.0f + truncf(l1 * 27.0f + 0.5f);
    const float tl = 21.0f + truncf(l2 * 7.0f + 0.5f);
    const float w_off = fmaxf(tx - tl, 0.0f);
    const float h_off = fmaxf(ty - tl, 0.0f);
    const float w_end = fminf(tx + tl, 108.0f);
    const float h_end = fminf(ty + tl, 108.0f);

    // ---- row table: built once (one expf pass, threads 0..107) ----
    if (tid < IN_SZ) {
        float fj  = (float)tid;
        float sr  = w_off + (fj * (w_end - w_off - 1.0f)) / 107.0f;  // reference order
        float flr = fminf(fmaxf(floorf(sr), 0.0f), 107.0f);
        int   r0  = (int)flr;
        int   r1  = min(r0 + 1, 107);
        float fr  = sr - flr;
        float4 p;
        p.x = (1.0f - fr) * maskv((float)r0, w_off, w_end);
        p.y = fr * maskv((float)r1, w_off, w_end);
        p.z = __int_as_float(r0 * IN_SZ);
        p.w = __int_as_float(r1 * IN_SZ);
        s_row[tid] = p;
    }

    // ---- per-lane column params (cols 2l, 2l+1), loop-invariant ----
    const float cspan = h_end - h_off - 1.0f;
    const int kA = min(2 * l, 107), kB = min(2 * l + 1, 107);
    float scA  = h_off + ((float)kA * cspan) / 107.0f;
    float flA  = fminf(fmaxf(floorf(scA), 0.0f), 107.0f);
    int   c0A  = (int)flA;
    float fcA  = scA - flA;
    float wc0A = (1.0f - fcA) * maskv((float)c0A, h_off, h_end);
    float wc1A = fcA * maskv((float)min(c0A + 1, 107), h_off, h_end);
    float scB  = h_off + ((float)kB * cspan) / 107.0f;
    float flB  = fminf(fmaxf(floorf(scB), 0.0f), 107.0f);
    int   c0B  = (int)flB;
    float fcB  = scB - flB;
    float wc0B = (1.0f - fcB) * maskv((float)c0B, h_off, h_end);
    float wc1B = fcB * maskv((float)min(c0B + 1, 107), h_off, h_end);

    // ---- 4-col window [e, e+3]: even start, never crosses channel end ----
    // covers taps: c0A,c0A+1 (rel p,p+1) and c0B,c0B+1 (rel q,q+1).
    // When p+1>3 (c0A==107) or q+1>3 (c0B==107) the corresponding weight is
    // EXACTLY zero (box coords integer-valued -> fc==0), so clamping the tap
    // index to 3 is exact.
    const int e  = min(c0A & ~1, 104);
    const int p_ = c0A - e;                   // 0..3
    const int q_ = c0B - e;                   // 0..3
    const int t2 = min(p_ + 1, 3);
    const int t3 = min(q_ + 1, 3);
    // window weight vectors (zeros in unused slots; built once)
    float Wx0 = (p_ == 0 ? wc0A : 0.0f) + (t2 == 0 ? wc1A : 0.0f);
    float Wx1 = (p_ == 1 ? wc0A : 0.0f) + (t2 == 1 ? wc1A : 0.0f);
    float Wx2 = (p_ == 2 ? wc0A : 0.0f) + (t2 == 2 ? wc1A : 0.0f);
    float Wx3 = (p_ == 3 ? wc0A : 0.0f) + (t2 == 3 ? wc1A : 0.0f);
    float Wy0 = (q_ == 0 ? wc0B : 0.0f) + (t3 == 0 ? wc1B : 0.0f);
    float Wy1 = (q_ == 1 ? wc0B : 0.0f) + (t3 == 1 ? wc1B : 0.0f);
    float Wy2 = (q_ == 2 ? wc0B : 0.0f) + (t3 == 2 ? wc1B : 0.0f);
    float Wy3 = (q_ == 3 ? wc0B : 0.0f) + (t3 == 3 ? wc1B : 0.0f);

    __syncthreads();

    const float* __restrict__ srce = images + (size_t)blk * NPIX + e;  // lane window base
    float*       __restrict__ dstl = out    + (size_t)blk * NPIX + 2 * l;

    // ---- prologue: rows seq 0,1 (j = w, w+4) ----
    float4 pA = s_row[w];
    float4 pB = s_row[w + 4];
    f32x4 Aa = ld4u(srce + __float_as_int(pA.z));
    f32x4 Ba = ld4u(srce + __float_as_int(pA.w));
    f32x4 Ab = ld4u(srce + __float_as_int(pB.z));
    f32x4 Bb = ld4u(srce + __float_as_int(pB.w));

    for (int k = 0; k < 14; ++k) {
        // prefetch next iteration's two rows (seq 2k+2, 2k+3; tail-clamped)
        float4 pA2 = pA, pB2 = pB;
        f32x4 Aa2 = Aa, Ba2 = Ba, Ab2 = Ab, Bb2 = Bb;
        if (k < 13) {
            int a2 = 2 * k + 2, b2 = min(2 * k + 3, 26);
            pA2 = s_row[w + 4 * a2];
            pB2 = s_row[w + 4 * b2];
            Aa2 = ld4u(srce + __float_as_int(pA2.z));
            Ba2 = ld4u(srce + __float_as_int(pA2.w));
            Ab2 = ld4u(srce + __float_as_int(pB2.z));
            Bb2 = ld4u(srce + __float_as_int(pB2.w));
        }
        // ---- row a = seq 2k (j = w + 8k) ----
        {
            f32x4 M = Aa * pA.x + Ba * pA.y;      // v_pk_fma_f32 x2
            f32x2 o;
            o.x = M.x * Wx0 + M.y * Wx1 + M.z * Wx2 + M.w * Wx3;
            o.y = M.x * Wy0 + M.y * Wy1 + M.z * Wy2 + M.w * Wy3;
            if (l < 54) *(f32x2*)(dstl + (w + 8 * k) * IN_SZ) = o;
        }
        // ---- row b = seq 2k+1 (j = w + 8k + 4; skipped at k=13) ----
        if (k < 13) {
            f32x4 M = Ab * pB.x + Bb * pB.y;
            f32x2 o;
            o.x = M.x * Wx0 + M.y * Wx1 + M.z * Wx2 + M.w * Wx3;
            o.y = M.x * Wy0 + M.y * Wy1 + M.z * Wy2 + M.w * Wy3;
            if (l < 54) *(f32x2*)(dstl + (w + 8 * k + 4) * IN_SZ) = o;
        }
        pA = pA2; pB = pB2;
        Aa = Aa2; Ba = Ba2; Ab = Ab2; Bb = Bb2;
    }
}

extern "C" void kernel_launch(void* const* d_in, const int* in_sizes, int n_in,
                              void* d_out, int out_size, void* d_ws, size_t ws_size,
                              hipStream_t stream) {
    const float* images = (const float*)d_in[0];
    const float* locs   = (const float*)d_in[1];
    float* out = (float*)d_out;
    const int nimg = in_sizes[1] / 3;   // locs is [nimg, 3]
    attn_crop_kernel<<<dim3(nimg * 3), dim3(256), 0, stream>>>(images, locs, out);
}